// Round 4
// baseline (1428.002 us; speedup 1.0000x reference)
//
#include <hip/hip_runtime.h>
#include <hip/hip_bf16.h>

#define NN 100000
#define NE 1600000
#define FF 64
#define HH 128
#define OO 10
#define NL 3
#define NB 391
#define BCAP 5376
#define LNEPS 1e-5f

typedef short s8v __attribute__((ext_vector_type(8)));   // 8 bf16 = 4 VGPR
typedef float f32x4 __attribute__((ext_vector_type(4)));
typedef float f32x2 __attribute__((ext_vector_type(2)));

__device__ __forceinline__ unsigned short f2b(float f){
  unsigned u = __float_as_uint(f);
  unsigned r = (u + 0x7FFFu + ((u>>16)&1u)) >> 16;
  return (unsigned short)r;
}
__device__ __forceinline__ float b2f(unsigned short b){
  return __uint_as_float(((unsigned)b)<<16);
}

#if __has_builtin(__builtin_amdgcn_cvt_pk_f32_fp8) && __has_builtin(__builtin_amdgcn_cvt_pk_fp8_f32)
__device__ __forceinline__ unsigned char f8enc(float x){
  int p = __builtin_amdgcn_cvt_pk_fp8_f32(x, x, 0, false);
  return (unsigned char)(p & 0xFF);
}
__device__ __forceinline__ void f8dec4(unsigned u, float* o){
  f32x2 lo = __builtin_amdgcn_cvt_pk_f32_fp8(u, false);
  f32x2 hi = __builtin_amdgcn_cvt_pk_f32_fp8(u, true);
  o[0]=lo[0]; o[1]=lo[1]; o[2]=hi[0]; o[3]=hi[1];
}
#else
#include <hip/hip_fp8.h>
__device__ __forceinline__ unsigned char f8enc(float x){
  __hip_fp8_e4m3 q(x); return (unsigned char)q.__x;
}
__device__ __forceinline__ void f8dec4(unsigned u, float* o){
  for(int i=0;i<4;i++){
    __hip_fp8_e4m3 q; q.__x = (unsigned char)(u>>(8*i));
    o[i] = (float)q;
  }
}
#endif

// ---------------- bucketed CSR build ----------------
__global__ __launch_bounds__(256) void k_bcount(const int* __restrict__ dst, int* __restrict__ bcnt){
  __shared__ int h[NB];
  for(int i=threadIdx.x;i<NB;i+=256) h[i]=0;
  __syncthreads();
  int base = blockIdx.x*6400;
  for(int i=threadIdx.x;i<6400;i+=256){
    int e = base+i;
    if(e<NE) atomicAdd(&h[((unsigned)dst[e])>>8],1);
  }
  __syncthreads();
  for(int i=threadIdx.x;i<NB;i+=256) if(h[i]) atomicAdd(&bcnt[i],h[i]);
}

__global__ void k_bscan(const int* __restrict__ bcnt, int* __restrict__ boff, int* __restrict__ rowoff){
  __shared__ int s[512];
  int t=threadIdx.x;
  int v = (t<NB)? bcnt[t]:0;
  s[t]=v; __syncthreads();
  for(int off=1;off<512;off<<=1){
    int x=(t>=off)?s[t-off]:0;
    __syncthreads();
    s[t]+=x;
    __syncthreads();
  }
  if(t<NB) boff[t]=s[t]-v;
  if(t==0) rowoff[NN]=NE;
}

__global__ void k_bscatter(const int* __restrict__ src, const int* __restrict__ dst,
                           const int* __restrict__ boff, int* __restrict__ bcur,
                           unsigned* __restrict__ ebuf){
  int e = blockIdx.x*256+threadIdx.x;
  if(e<NE){
    int d = dst[e];
    int b = ((unsigned)d)>>8;
    int p = atomicAdd(&bcur[b],1);
    ebuf[boff[b]+p] = (unsigned)src[e] | ((unsigned)(d&255)<<20);
  }
}

__global__ __launch_bounds__(256) void k_bsort(const unsigned* __restrict__ ebuf, const int* __restrict__ bcnt,
                                               const int* __restrict__ boff, int* __restrict__ rowoff,
                                               float* __restrict__ invd, int* __restrict__ csr){
  __shared__ unsigned el[BCAP];
  __shared__ int dg[256], sc[256], cu[256];
  int b=blockIdx.x, t=threadIdx.x;
  int c = bcnt[b]; if(c>BCAP) c=BCAP;
  int base = boff[b];
  for(int i=t;i<c;i+=256) el[i]=ebuf[base+i];
  dg[t]=0;
  __syncthreads();
  for(int i=t;i<c;i+=256) atomicAdd(&dg[el[i]>>20],1);
  __syncthreads();
  int v = dg[t];
  sc[t]=v; __syncthreads();
  for(int off=1;off<256;off<<=1){
    int x=(t>=off)?sc[t-off]:0;
    __syncthreads();
    sc[t]+=x;
    __syncthreads();
  }
  int excl = sc[t]-v;
  int node = b*256+t;
  if(node<NN){
    rowoff[node]=base+excl;
    invd[node]=1.0f/fmaxf((float)v,1.0f);
  }
  cu[t]=excl;
  __syncthreads();
  for(int i=t;i<c;i+=256){
    unsigned e=el[i];
    int d=e>>20;
    int p=atomicAdd(&cu[d],1);
    csr[base+p] = (int)(e & 0xFFFFFu);
  }
}

// ---------------- input conversion & weight repack ----------------
__global__ void k_cvtin(const float* __restrict__ x, unsigned* __restrict__ xb, int n4){
  int i = blockIdx.x*256+threadIdx.x;
  if(i<n4){
    float4 v = *(const float4*)&x[i*4];
    uint2 p;
    p.x = (unsigned)f2b(v.x) | ((unsigned)f2b(v.y)<<16);
    p.y = (unsigned)f2b(v.z) | ((unsigned)f2b(v.w)<<16);
    *(uint2*)&xb[i*2] = p;
  }
}

// frag-ready: wf[((kcb*8+nt)*64+l)*8+j] = bf16(W[(kcb*32+8*(l>>4)+j)*128 + nt*16+(l&15)])
__global__ void k_repack(const float* __restrict__ W1, const float* __restrict__ W2,
                         const float* __restrict__ Ws, const float* __restrict__ Wn,
                         unsigned short* __restrict__ wf){
  int t = blockIdx.x*256+threadIdx.x;
  if(t >= 122880) return;
  const float* src; int rem;
  if(t < 8192){ src = W1; rem = t; }
  else {
    int u = t - 8192;
    int m = u >> 14; rem = u & 16383;
    if(m==0) src = W2;
    else if(m<=3) src = Ws + (size_t)(m-1)*HH*HH;
    else src = Wn + (size_t)(m-4)*HH*HH;
  }
  int j = rem&7, l=(rem>>3)&63, nt=(rem>>9)&7, kcb=rem>>12;
  int k = kcb*32 + 8*(l>>4) + j;
  int n = nt*16 + (l&15);
  wf[t] = f2b(src[(size_t)k*HH + n]);
}

// ---------------- mean aggregation: fp8 gather, one wave per node ----------------
__global__ __launch_bounds__(256) void k_agg(const unsigned* __restrict__ hf8, const int* __restrict__ csr,
                                             const int* __restrict__ rowoff, const float* __restrict__ invd,
                                             unsigned* __restrict__ aggb){
  int wave=threadIdx.x>>6, lane=threadIdx.x&63;
  int n = blockIdx.x*4+wave;
  if(n>=NN) return;
  int beg=rowoff[n], end=rowoff[n+1];
  int c = lane&31, half=lane>>5;
  float a0=0.f,a1=0.f,a2=0.f,a3=0.f;
  int j=beg;
  for(; j+4<=end; j+=4){
    int s0=csr[j+half], s1=csr[j+2+half];
    unsigned u0=hf8[(size_t)s0*32+c], u1=hf8[(size_t)s1*32+c];
    float d0[4], d1[4];
    f8dec4(u0,d0); f8dec4(u1,d1);
    a0+=d0[0]+d1[0]; a1+=d0[1]+d1[1]; a2+=d0[2]+d1[2]; a3+=d0[3]+d1[3];
  }
  for(; j+2<=end; j+=2){
    int s0=csr[j+half];
    unsigned u0=hf8[(size_t)s0*32+c];
    float d0[4];
    f8dec4(u0,d0);
    a0+=d0[0]; a1+=d0[1]; a2+=d0[2]; a3+=d0[3];
  }
  if(j<end && half==0){
    int s0=csr[j];
    unsigned u0=hf8[(size_t)s0*32+c];
    float d0[4];
    f8dec4(u0,d0);
    a0+=d0[0]; a1+=d0[1]; a2+=d0[2]; a3+=d0[3];
  }
  a0+=__shfl_xor(a0,32); a1+=__shfl_xor(a1,32);
  a2+=__shfl_xor(a2,32); a3+=__shfl_xor(a3,32);
  if(half==0){
    float s=invd[n];
    uint2 p;
    p.x = (unsigned)f2b(a0*s) | ((unsigned)f2b(a1*s)<<16);
    p.y = (unsigned)f2b(a2*s) | ((unsigned)f2b(a3*s)<<16);
    *(uint2*)&aggb[(size_t)n*64 + 2*c] = p;
  }
}

// ---------------- MFMA GEMM: out = [LN](act(A@W [+ A2@W2] + b)), bf16 out (+fp8 shadow) ----
template<int K, int DUAL, int RELU, int LN, int F8>
__global__ __launch_bounds__(256) void k_mfma(
    const unsigned short* __restrict__ A, const unsigned short* __restrict__ A2,
    const unsigned short* __restrict__ Wf, const unsigned short* __restrict__ Wf2,
    const float* __restrict__ bias, const float* __restrict__ lng, const float* __restrict__ lnb,
    unsigned short* __restrict__ out, unsigned char* __restrict__ hf8)
{
  constexpr int KC = K/32;
  __shared__ unsigned short Wl[KC*8*64*8];
  __shared__ unsigned short Wl2[DUAL ? KC*8*64*8 : 8];
  int tid = threadIdx.x;
  {
    const int tot = KC*8*64*8/8;
    for(int i=tid;i<tot;i+=256){
      ((uint4*)Wl)[i] = ((const uint4*)Wf)[i];
      if(DUAL) ((uint4*)Wl2)[i] = ((const uint4*)Wf2)[i];
    }
  }
  __syncthreads();
  int l = tid&63, wv = tid>>6;
  int grp = l>>4, lc = l&15;
  int node0 = blockIdx.x*64 + wv*16;
  int arow = node0 + lc; if(arow > NN-1) arow = NN-1;
  f32x4 acc[8] = {};
  const s8v* Wv  = (const s8v*)Wl;
  const s8v* Wv2 = (const s8v*)Wl2;
  #pragma unroll
  for(int kcb=0;kcb<KC;kcb++){
    s8v a = *(const s8v*)&A[(size_t)arow*K + kcb*32 + 8*grp];
    s8v a2;
    if(DUAL) a2 = *(const s8v*)&A2[(size_t)arow*K + kcb*32 + 8*grp];
    #pragma unroll
    for(int nt=0;nt<8;nt++){
      acc[nt] = __builtin_amdgcn_mfma_f32_16x16x32_bf16(a, Wv[(kcb*8+nt)*64 + l], acc[nt], 0,0,0);
      if(DUAL)
        acc[nt] = __builtin_amdgcn_mfma_f32_16x16x32_bf16(a2, Wv2[(kcb*8+nt)*64 + l], acc[nt], 0,0,0);
    }
  }
  float bc[8], gc[8], oc[8];
  #pragma unroll
  for(int nt=0;nt<8;nt++){
    bc[nt] = bias[nt*16+lc];
    if(LN){ gc[nt]=lng[nt*16+lc]; oc[nt]=lnb[nt*16+lc]; }
  }
  #pragma unroll
  for(int r=0;r<4;r++){
    float x[8]; float s=0.f, ss=0.f;
    #pragma unroll
    for(int nt=0;nt<8;nt++){
      float v = acc[nt][r] + bc[nt];
      if(RELU) v = fmaxf(v, 0.f);
      x[nt]=v; s+=v; ss+=v*v;
    }
    if(LN){
      #pragma unroll
      for(int m=1;m<=8;m<<=1){ s+=__shfl_xor(s,m); ss+=__shfl_xor(ss,m); }
      float mu = s*(1.0f/HH);
      float var = ss*(1.0f/HH) - mu*mu;
      float rs = rsqrtf(var + LNEPS);
      #pragma unroll
      for(int nt=0;nt<8;nt++) x[nt] = gc[nt]*(x[nt]-mu)*rs + oc[nt];
    }
    int node = node0 + grp*4 + r;
    if(node<NN){
      #pragma unroll
      for(int nt=0;nt<8;nt++) out[(size_t)node*HH + nt*16 + lc] = f2b(x[nt]);
      if(F8){
        #pragma unroll
        for(int nt=0;nt<8;nt++) hf8[(size_t)node*HH + nt*16 + lc] = f8enc(x[nt]);
      }
    }
  }
}

// ---------------- graph mean + output head ----------------
__global__ void k_mean(const unsigned short* __restrict__ hb, float* __restrict__ g){
  int col=threadIdx.x;
  float s=0.f;
  for(int n=blockIdx.x; n<NN; n+=gridDim.x) s += b2f(hb[(size_t)n*HH + col]);
  atomicAdd(&g[col], s);
}

__global__ void k_out(const float* __restrict__ g, const float* __restrict__ Wout,
                      const float* __restrict__ bout, float* __restrict__ out){
  int o=threadIdx.x;
  if(o<OO){
    float acc=bout[o];
    for(int k=0;k<HH;k++) acc = fmaf(g[k]*(1.0f/NN), Wout[k*OO+o], acc);
    out[o]=acc;
  }
}

extern "C" void kernel_launch(void* const* d_in, const int* in_sizes, int n_in,
                              void* d_out, int out_size, void* d_ws, size_t ws_size,
                              hipStream_t stream){
  const float* nodes = (const float*)d_in[0];
  const int*   src   = (const int*)d_in[1];
  const int*   dst   = (const int*)d_in[2];
  const float* W_in1 = (const float*)d_in[3];
  const float* b_in1 = (const float*)d_in[4];
  const float* W_in2 = (const float*)d_in[5];
  const float* b_in2 = (const float*)d_in[6];
  const float* W_self  = (const float*)d_in[7];
  const float* W_neigh = (const float*)d_in[8];
  const float* b_sage  = (const float*)d_in[9];
  const float* ln_g    = (const float*)d_in[10];
  const float* ln_b    = (const float*)d_in[11];
  const float* W_out   = (const float*)d_in[12];
  const float* b_out   = (const float*)d_in[13];

  char* w=(char*)d_ws;
  unsigned short* hb   = (unsigned short*)w; w += (size_t)NN*HH*2;   // 25.6 MB
  unsigned short* aggb = (unsigned short*)w; w += (size_t)NN*HH*2;   // 25.6 MB
  unsigned short* xb   = (unsigned short*)w; w += (size_t)NN*FF*2;   // 12.8 MB
  unsigned char*  hf8  = (unsigned char*)w;  w += (size_t)NN*HH;     // 12.8 MB fp8 shadow
  unsigned short* wf   = (unsigned short*)w; w += (size_t)122880*2;
  unsigned* ebuf = (unsigned*)w; w += (size_t)NE*4;                  // 6.4 MB
  int* csr    = (int*)w;   w += (size_t)NE*4;                        // 6.4 MB
  int* rowoff = (int*)w;   w += (size_t)(NN+8)*4;
  float* invd = (float*)w; w += (size_t)NN*4;
  int* bcnt   = (int*)w;   w += (size_t)(NB+1)*4;
  int* boff   = (int*)w;   w += (size_t)(NB+1)*4;
  int* bcur   = (int*)w;   w += (size_t)(NB+1)*4;
  float* gsum = (float*)w; w += 128*4;

  hipMemsetAsync(bcnt, 0, (size_t)(NB+1)*4, stream);
  hipMemsetAsync(bcur, 0, (size_t)(NB+1)*4, stream);
  hipMemsetAsync(gsum, 0, 128*4, stream);

  k_bcount<<<250,256,0,stream>>>(dst,bcnt);
  k_bscan<<<1,512,0,stream>>>(bcnt,boff,rowoff);
  k_bscatter<<<(NE+255)/256,256,0,stream>>>(src,dst,boff,bcur,ebuf);
  k_bsort<<<NB,256,0,stream>>>(ebuf,bcnt,boff,rowoff,invd,csr);

  k_cvtin<<<((NN*FF/4)+255)/256,256,0,stream>>>(nodes,(unsigned*)xb, NN*FF/4);
  k_repack<<<(122880+255)/256,256,0,stream>>>(W_in1,W_in2,W_self,W_neigh,wf);

  const int GB = (NN+63)/64;
  // input MLP
  k_mfma<FF,0,1,0,0><<<GB,256,0,stream>>>(xb,nullptr, wf, nullptr, b_in1,nullptr,nullptr, aggb, nullptr);
  k_mfma<HH,0,0,0,1><<<GB,256,0,stream>>>(aggb,nullptr, wf+8192, nullptr, b_in2,nullptr,nullptr, hb, hf8);

  for(int l=0;l<NL;l++){
    k_agg<<<(NN+3)/4,256,0,stream>>>((const unsigned*)hf8,csr,rowoff,invd,(unsigned*)aggb);
    if(l<NL-1)
      k_mfma<HH,1,1,1,1><<<GB,256,0,stream>>>(hb, aggb,
          wf+24576+(size_t)l*16384, wf+73728+(size_t)l*16384,
          b_sage+(size_t)l*HH, ln_g+(size_t)l*HH, ln_b+(size_t)l*HH, hb, hf8);
    else
      k_mfma<HH,1,1,1,0><<<GB,256,0,stream>>>(hb, aggb,
          wf+24576+(size_t)l*16384, wf+73728+(size_t)l*16384,
          b_sage+(size_t)l*HH, ln_g+(size_t)l*HH, ln_b+(size_t)l*HH, hb, nullptr);
  }
  k_mean<<<256,128,0,stream>>>(hb,gsum);
  k_out<<<1,64,0,stream>>>(gsum,W_out,b_out,(float*)d_out);
}

// Round 5
// 470.697 us; speedup vs baseline: 3.0338x; 3.0338x over previous
//
#include <hip/hip_runtime.h>
#include <hip/hip_bf16.h>

#define NN 100000
#define NE 1600000
#define FF 64
#define HH 128
#define OO 10
#define NL 3
#define NB 391
#define NBLK 250
#define CHUNK 6400
#define BCAP 5376
#define LNEPS 1e-5f

typedef short s8v __attribute__((ext_vector_type(8)));   // 8 bf16 = 4 VGPR
typedef float f32x4 __attribute__((ext_vector_type(4)));
typedef float f32x2 __attribute__((ext_vector_type(2)));

__device__ __forceinline__ unsigned short f2b(float f){
  unsigned u = __float_as_uint(f);
  unsigned r = (u + 0x7FFFu + ((u>>16)&1u)) >> 16;
  return (unsigned short)r;
}
__device__ __forceinline__ float b2f(unsigned short b){
  return __uint_as_float(((unsigned)b)<<16);
}

#if __has_builtin(__builtin_amdgcn_cvt_pk_f32_fp8) && __has_builtin(__builtin_amdgcn_cvt_pk_fp8_f32)
__device__ __forceinline__ unsigned char f8enc(float x){
  int p = __builtin_amdgcn_cvt_pk_fp8_f32(x, x, 0, false);
  return (unsigned char)(p & 0xFF);
}
__device__ __forceinline__ void f8dec4(unsigned u, float* o){
  f32x2 lo = __builtin_amdgcn_cvt_pk_f32_fp8(u, false);
  f32x2 hi = __builtin_amdgcn_cvt_pk_f32_fp8(u, true);
  o[0]=lo[0]; o[1]=lo[1]; o[2]=hi[0]; o[3]=hi[1];
}
#else
#include <hip/hip_fp8.h>
__device__ __forceinline__ unsigned char f8enc(float x){
  __hip_fp8_e4m3 q(x); return (unsigned char)q.__x;
}
__device__ __forceinline__ void f8dec4(unsigned u, float* o){
  for(int i=0;i<4;i++){
    __hip_fp8_e4m3 q; q.__x = (unsigned char)(u>>(8*i));
    o[i] = (float)q;
  }
}
#endif

// ---------------- bucketed CSR build (contention-free radix) ----------------
__global__ __launch_bounds__(256) void k_bcount(const int* __restrict__ dst, int* __restrict__ bcnt,
                                                int* __restrict__ blockcnt){
  __shared__ int h[NB];
  for(int i=threadIdx.x;i<NB;i+=256) h[i]=0;
  __syncthreads();
  int base = blockIdx.x*CHUNK;
  for(int i=threadIdx.x;i<CHUNK;i+=256){
    int e = base+i;
    if(e<NE) atomicAdd(&h[((unsigned)dst[e])>>8],1);
  }
  __syncthreads();
  for(int i=threadIdx.x;i<NB;i+=256){
    int v=h[i];
    blockcnt[i*256 + blockIdx.x] = v;
    if(v) atomicAdd(&bcnt[i],v);
  }
}

__global__ void k_bscan(const int* __restrict__ bcnt, int* __restrict__ boff, int* __restrict__ rowoff){
  __shared__ int s[512];
  int t=threadIdx.x;
  int v = (t<NB)? bcnt[t]:0;
  s[t]=v; __syncthreads();
  for(int off=1;off<512;off<<=1){
    int x=(t>=off)?s[t-off]:0;
    __syncthreads();
    s[t]+=x;
    __syncthreads();
  }
  if(t<NB) boff[t]=s[t]-v;
  if(t==0) rowoff[NN]=NE;
}

// per-bucket exclusive prefix over block counts: pref[k][b] = boff[k] + sum_{b'<b} blockcnt[k][b']
__global__ void k_prefix(const int* __restrict__ blockcnt, const int* __restrict__ boff,
                         int* __restrict__ pref){
  __shared__ int s[256];
  int k=blockIdx.x, t=threadIdx.x;
  int v = (t<NBLK)? blockcnt[k*256+t] : 0;
  s[t]=v; __syncthreads();
  for(int off=1;off<256;off<<=1){
    int x=(t>=off)?s[t-off]:0;
    __syncthreads();
    s[t]+=x;
    __syncthreads();
  }
  if(t<NBLK) pref[k*256+t] = boff[k] + s[t]-v;
}

__global__ __launch_bounds__(256) void k_bscatter(const int* __restrict__ src, const int* __restrict__ dst,
                                                  const int* __restrict__ pref, unsigned* __restrict__ ebuf){
  __shared__ int cur[NB];
  __shared__ int pb[NB];
  for(int i=threadIdx.x;i<NB;i+=256){ cur[i]=0; pb[i]=pref[i*256+blockIdx.x]; }
  __syncthreads();
  int base=blockIdx.x*CHUNK;
  for(int i=threadIdx.x;i<CHUNK;i+=256){
    int e=base+i;
    if(e<NE){
      int d=dst[e];
      int k=((unsigned)d)>>8;
      int r=atomicAdd(&cur[k],1);
      ebuf[pb[k]+r] = (unsigned)src[e] | ((unsigned)(d&255)<<20);
    }
  }
}

__global__ __launch_bounds__(256) void k_bsort(const unsigned* __restrict__ ebuf, const int* __restrict__ bcnt,
                                               const int* __restrict__ boff, int* __restrict__ rowoff,
                                               float* __restrict__ invd, int* __restrict__ csr){
  __shared__ unsigned el[BCAP];
  __shared__ int dg[256], sc[256], cu[256];
  int b=blockIdx.x, t=threadIdx.x;
  int c = bcnt[b]; if(c>BCAP) c=BCAP;
  int base = boff[b];
  for(int i=t;i<c;i+=256) el[i]=ebuf[base+i];
  dg[t]=0;
  __syncthreads();
  for(int i=t;i<c;i+=256) atomicAdd(&dg[el[i]>>20],1);
  __syncthreads();
  int v = dg[t];
  sc[t]=v; __syncthreads();
  for(int off=1;off<256;off<<=1){
    int x=(t>=off)?sc[t-off]:0;
    __syncthreads();
    sc[t]+=x;
    __syncthreads();
  }
  int excl = sc[t]-v;
  int node = b*256+t;
  if(node<NN){
    rowoff[node]=base+excl;
    invd[node]=1.0f/fmaxf((float)v,1.0f);
  }
  cu[t]=excl;
  __syncthreads();
  for(int i=t;i<c;i+=256){
    unsigned e=el[i];
    int d=e>>20;
    int p=atomicAdd(&cu[d],1);
    csr[base+p] = (int)(e & 0xFFFFFu);
  }
}

// ---------------- input conversion & weight repack ----------------
__global__ void k_cvtin(const float* __restrict__ x, unsigned* __restrict__ xb, int n4){
  int i = blockIdx.x*256+threadIdx.x;
  if(i<n4){
    float4 v = *(const float4*)&x[i*4];
    uint2 p;
    p.x = (unsigned)f2b(v.x) | ((unsigned)f2b(v.y)<<16);
    p.y = (unsigned)f2b(v.z) | ((unsigned)f2b(v.w)<<16);
    *(uint2*)&xb[i*2] = p;
  }
}

// frag-ready: wf[((kcb*8+nt)*64+l)*8+j] = bf16(W[(kcb*32+8*(l>>4)+j)*128 + nt*16+(l&15)])
__global__ void k_repack(const float* __restrict__ W1, const float* __restrict__ W2,
                         const float* __restrict__ Ws, const float* __restrict__ Wn,
                         unsigned short* __restrict__ wf){
  int t = blockIdx.x*256+threadIdx.x;
  if(t >= 122880) return;
  const float* src; int rem;
  if(t < 8192){ src = W1; rem = t; }
  else {
    int u = t - 8192;
    int m = u >> 14; rem = u & 16383;
    if(m==0) src = W2;
    else if(m<=3) src = Ws + (size_t)(m-1)*HH*HH;
    else src = Wn + (size_t)(m-4)*HH*HH;
  }
  int j = rem&7, l=(rem>>3)&63, nt=(rem>>9)&7, kcb=rem>>12;
  int k = kcb*32 + 8*(l>>4) + j;
  int n = nt*16 + (l&15);
  wf[t] = f2b(src[(size_t)k*HH + n]);
}

// ---------------- mean aggregation: fp8 gather, one wave per node ----------------
__global__ __launch_bounds__(256) void k_agg(const unsigned* __restrict__ hf8, const int* __restrict__ csr,
                                             const int* __restrict__ rowoff, const float* __restrict__ invd,
                                             unsigned* __restrict__ aggb){
  int wave=threadIdx.x>>6, lane=threadIdx.x&63;
  int n = blockIdx.x*4+wave;
  if(n>=NN) return;
  int beg=rowoff[n], end=rowoff[n+1];
  int c = lane&31, half=lane>>5;
  float a0=0.f,a1=0.f,a2=0.f,a3=0.f;
  int j=beg;
  for(; j+4<=end; j+=4){
    int s0=csr[j+half], s1=csr[j+2+half];
    unsigned u0=hf8[(size_t)s0*32+c], u1=hf8[(size_t)s1*32+c];
    float d0[4], d1[4];
    f8dec4(u0,d0); f8dec4(u1,d1);
    a0+=d0[0]+d1[0]; a1+=d0[1]+d1[1]; a2+=d0[2]+d1[2]; a3+=d0[3]+d1[3];
  }
  for(; j+2<=end; j+=2){
    int s0=csr[j+half];
    unsigned u0=hf8[(size_t)s0*32+c];
    float d0[4];
    f8dec4(u0,d0);
    a0+=d0[0]; a1+=d0[1]; a2+=d0[2]; a3+=d0[3];
  }
  if(j<end && half==0){
    int s0=csr[j];
    unsigned u0=hf8[(size_t)s0*32+c];
    float d0[4];
    f8dec4(u0,d0);
    a0+=d0[0]; a1+=d0[1]; a2+=d0[2]; a3+=d0[3];
  }
  a0+=__shfl_xor(a0,32); a1+=__shfl_xor(a1,32);
  a2+=__shfl_xor(a2,32); a3+=__shfl_xor(a3,32);
  if(half==0){
    float s=invd[n];
    uint2 p;
    p.x = (unsigned)f2b(a0*s) | ((unsigned)f2b(a1*s)<<16);
    p.y = (unsigned)f2b(a2*s) | ((unsigned)f2b(a3*s)<<16);
    *(uint2*)&aggb[(size_t)n*64 + 2*c] = p;
  }
}

// ---------------- MFMA GEMM: out = [LN](act(A@W [+ A2@W2] + b)), bf16 out (+fp8 shadow) ----
template<int K, int DUAL, int RELU, int LN, int F8>
__global__ __launch_bounds__(256) void k_mfma(
    const unsigned short* __restrict__ A, const unsigned short* __restrict__ A2,
    const unsigned short* __restrict__ Wf, const unsigned short* __restrict__ Wf2,
    const float* __restrict__ bias, const float* __restrict__ lng, const float* __restrict__ lnb,
    unsigned short* __restrict__ out, unsigned char* __restrict__ hf8)
{
  constexpr int KC = K/32;
  __shared__ unsigned short Wl[KC*8*64*8];
  __shared__ unsigned short Wl2[DUAL ? KC*8*64*8 : 8];
  int tid = threadIdx.x;
  {
    const int tot = KC*8*64*8/8;
    for(int i=tid;i<tot;i+=256){
      ((uint4*)Wl)[i] = ((const uint4*)Wf)[i];
      if(DUAL) ((uint4*)Wl2)[i] = ((const uint4*)Wf2)[i];
    }
  }
  __syncthreads();
  int l = tid&63, wv = tid>>6;
  int grp = l>>4, lc = l&15;
  int node0 = blockIdx.x*64 + wv*16;
  int arow = node0 + lc; if(arow > NN-1) arow = NN-1;
  f32x4 acc[8] = {};
  const s8v* Wv  = (const s8v*)Wl;
  const s8v* Wv2 = (const s8v*)Wl2;
  #pragma unroll
  for(int kcb=0;kcb<KC;kcb++){
    s8v a = *(const s8v*)&A[(size_t)arow*K + kcb*32 + 8*grp];
    s8v a2;
    if(DUAL) a2 = *(const s8v*)&A2[(size_t)arow*K + kcb*32 + 8*grp];
    #pragma unroll
    for(int nt=0;nt<8;nt++){
      acc[nt] = __builtin_amdgcn_mfma_f32_16x16x32_bf16(a, Wv[(kcb*8+nt)*64 + l], acc[nt], 0,0,0);
      if(DUAL)
        acc[nt] = __builtin_amdgcn_mfma_f32_16x16x32_bf16(a2, Wv2[(kcb*8+nt)*64 + l], acc[nt], 0,0,0);
    }
  }
  float bc[8], gc[8], oc[8];
  #pragma unroll
  for(int nt=0;nt<8;nt++){
    bc[nt] = bias[nt*16+lc];
    if(LN){ gc[nt]=lng[nt*16+lc]; oc[nt]=lnb[nt*16+lc]; }
  }
  #pragma unroll
  for(int r=0;r<4;r++){
    float x[8]; float s=0.f, ss=0.f;
    #pragma unroll
    for(int nt=0;nt<8;nt++){
      float v = acc[nt][r] + bc[nt];
      if(RELU) v = fmaxf(v, 0.f);
      x[nt]=v; s+=v; ss+=v*v;
    }
    if(LN){
      #pragma unroll
      for(int m=1;m<=8;m<<=1){ s+=__shfl_xor(s,m); ss+=__shfl_xor(ss,m); }
      float mu = s*(1.0f/HH);
      float var = ss*(1.0f/HH) - mu*mu;
      float rs = rsqrtf(var + LNEPS);
      #pragma unroll
      for(int nt=0;nt<8;nt++) x[nt] = gc[nt]*(x[nt]-mu)*rs + oc[nt];
    }
    int node = node0 + grp*4 + r;
    if(node<NN){
      #pragma unroll
      for(int nt=0;nt<8;nt++) out[(size_t)node*HH + nt*16 + lc] = f2b(x[nt]);
      if(F8){
        #pragma unroll
        for(int nt=0;nt<8;nt++) hf8[(size_t)node*HH + nt*16 + lc] = f8enc(x[nt]);
      }
    }
  }
}

// ---------------- graph mean + output head ----------------
__global__ void k_mean(const unsigned short* __restrict__ hb, float* __restrict__ g){
  int col=threadIdx.x;
  float s=0.f;
  for(int n=blockIdx.x; n<NN; n+=gridDim.x) s += b2f(hb[(size_t)n*HH + col]);
  atomicAdd(&g[col], s);
}

__global__ void k_out(const float* __restrict__ g, const float* __restrict__ Wout,
                      const float* __restrict__ bout, float* __restrict__ out){
  int o=threadIdx.x;
  if(o<OO){
    float acc=bout[o];
    for(int k=0;k<HH;k++) acc = fmaf(g[k]*(1.0f/NN), Wout[k*OO+o], acc);
    out[o]=acc;
  }
}

extern "C" void kernel_launch(void* const* d_in, const int* in_sizes, int n_in,
                              void* d_out, int out_size, void* d_ws, size_t ws_size,
                              hipStream_t stream){
  const float* nodes = (const float*)d_in[0];
  const int*   src   = (const int*)d_in[1];
  const int*   dst   = (const int*)d_in[2];
  const float* W_in1 = (const float*)d_in[3];
  const float* b_in1 = (const float*)d_in[4];
  const float* W_in2 = (const float*)d_in[5];
  const float* b_in2 = (const float*)d_in[6];
  const float* W_self  = (const float*)d_in[7];
  const float* W_neigh = (const float*)d_in[8];
  const float* b_sage  = (const float*)d_in[9];
  const float* ln_g    = (const float*)d_in[10];
  const float* ln_b    = (const float*)d_in[11];
  const float* W_out   = (const float*)d_in[12];
  const float* b_out   = (const float*)d_in[13];

  char* w=(char*)d_ws;
  unsigned short* hb   = (unsigned short*)w; w += (size_t)NN*HH*2;   // 25.6 MB
  unsigned short* aggb = (unsigned short*)w; w += (size_t)NN*HH*2;   // 25.6 MB
  unsigned short* xb   = (unsigned short*)w; w += (size_t)NN*FF*2;   // 12.8 MB
  unsigned char*  hf8  = (unsigned char*)w;  w += (size_t)NN*HH;     // 12.8 MB fp8 shadow
  unsigned short* wf   = (unsigned short*)w; w += (size_t)122880*2;
  unsigned* ebuf = (unsigned*)w; w += (size_t)NE*4;                  // 6.4 MB
  int* csr    = (int*)w;   w += (size_t)NE*4;                        // 6.4 MB
  int* rowoff = (int*)w;   w += (size_t)(NN+8)*4;
  float* invd = (float*)w; w += (size_t)NN*4;
  int* bcnt   = (int*)w;   w += (size_t)(NB+1)*4;
  int* boff   = (int*)w;   w += (size_t)(NB+1)*4;
  int* blockcnt=(int*)w;   w += (size_t)NB*256*4;                    // 0.4 MB
  int* pref   = (int*)w;   w += (size_t)NB*256*4;                    // 0.4 MB
  float* gsum = (float*)w; w += 128*4;

  hipMemsetAsync(bcnt, 0, (size_t)(NB+1)*4, stream);
  hipMemsetAsync(gsum, 0, 128*4, stream);

  k_bcount<<<NBLK,256,0,stream>>>(dst,bcnt,blockcnt);
  k_bscan<<<1,512,0,stream>>>(bcnt,boff,rowoff);
  k_prefix<<<NB,256,0,stream>>>(blockcnt,boff,pref);
  k_bscatter<<<NBLK,256,0,stream>>>(src,dst,pref,ebuf);
  k_bsort<<<NB,256,0,stream>>>(ebuf,bcnt,boff,rowoff,invd,csr);

  k_cvtin<<<((NN*FF/4)+255)/256,256,0,stream>>>(nodes,(unsigned*)xb, NN*FF/4);
  k_repack<<<(122880+255)/256,256,0,stream>>>(W_in1,W_in2,W_self,W_neigh,wf);

  const int GB = (NN+63)/64;
  // input MLP
  k_mfma<FF,0,1,0,0><<<GB,256,0,stream>>>(xb,nullptr, wf, nullptr, b_in1,nullptr,nullptr, aggb, nullptr);
  k_mfma<HH,0,0,0,1><<<GB,256,0,stream>>>(aggb,nullptr, wf+8192, nullptr, b_in2,nullptr,nullptr, hb, hf8);

  for(int l=0;l<NL;l++){
    k_agg<<<(NN+3)/4,256,0,stream>>>((const unsigned*)hf8,csr,rowoff,invd,(unsigned*)aggb);
    if(l<NL-1)
      k_mfma<HH,1,1,1,1><<<GB,256,0,stream>>>(hb, aggb,
          wf+24576+(size_t)l*16384, wf+73728+(size_t)l*16384,
          b_sage+(size_t)l*HH, ln_g+(size_t)l*HH, ln_b+(size_t)l*HH, hb, hf8);
    else
      k_mfma<HH,1,1,1,0><<<GB,256,0,stream>>>(hb, aggb,
          wf+24576+(size_t)l*16384, wf+73728+(size_t)l*16384,
          b_sage+(size_t)l*HH, ln_g+(size_t)l*HH, ln_b+(size_t)l*HH, hb, nullptr);
  }
  k_mean<<<256,128,0,stream>>>(hb,gsum);
  k_out<<<1,64,0,stream>>>(gsum,W_out,b_out,(float*)d_out);
}

// Round 6
// 404.183 us; speedup vs baseline: 3.5331x; 1.1646x over previous
//
#include <hip/hip_runtime.h>
#include <hip/hip_bf16.h>

#define NN 100000
#define NE 1600000
#define FF 64
#define HH 128
#define OO 10
#define NL 3
#define NB 391
#define NBLK 250
#define CHUNK 6400
#define BCAP 5376
#define LNEPS 1e-5f

typedef short s8v __attribute__((ext_vector_type(8)));   // 8 bf16 = 4 VGPR
typedef float f32x4 __attribute__((ext_vector_type(4)));
typedef float f32x2 __attribute__((ext_vector_type(2)));

__device__ __forceinline__ unsigned short f2b(float f){
  unsigned u = __float_as_uint(f);
  unsigned r = (u + 0x7FFFu + ((u>>16)&1u)) >> 16;
  return (unsigned short)r;
}
__device__ __forceinline__ float b2f(unsigned short b){
  return __uint_as_float(((unsigned)b)<<16);
}

#if __has_builtin(__builtin_amdgcn_cvt_pk_f32_fp8) && __has_builtin(__builtin_amdgcn_cvt_pk_fp8_f32)
__device__ __forceinline__ unsigned char f8enc(float x){
  int p = __builtin_amdgcn_cvt_pk_fp8_f32(x, x, 0, false);
  return (unsigned char)(p & 0xFF);
}
__device__ __forceinline__ void f8dec4(unsigned u, float* o){
  f32x2 lo = __builtin_amdgcn_cvt_pk_f32_fp8(u, false);
  f32x2 hi = __builtin_amdgcn_cvt_pk_f32_fp8(u, true);
  o[0]=lo[0]; o[1]=lo[1]; o[2]=hi[0]; o[3]=hi[1];
}
#else
#include <hip/hip_fp8.h>
__device__ __forceinline__ unsigned char f8enc(float x){
  __hip_fp8_e4m3 q(x); return (unsigned char)q.__x;
}
__device__ __forceinline__ void f8dec4(unsigned u, float* o){
  for(int i=0;i<4;i++){
    __hip_fp8_e4m3 q; q.__x = (unsigned char)(u>>(8*i));
    o[i] = (float)q;
  }
}
#endif

// ---------------- bucketed CSR build (contention-free radix) ----------------
__global__ __launch_bounds__(256) void k_bcount(const int* __restrict__ dst, int* __restrict__ bcnt,
                                                int* __restrict__ blockcnt){
  __shared__ int h[NB];
  for(int i=threadIdx.x;i<NB;i+=256) h[i]=0;
  __syncthreads();
  int base = blockIdx.x*CHUNK;
  for(int i=threadIdx.x;i<CHUNK;i+=256){
    int e = base+i;
    if(e<NE) atomicAdd(&h[((unsigned)dst[e])>>8],1);
  }
  __syncthreads();
  for(int i=threadIdx.x;i<NB;i+=256){
    int v=h[i];
    blockcnt[i*256 + blockIdx.x] = v;
    if(v) atomicAdd(&bcnt[i],v);
  }
}

__global__ void k_bscan(const int* __restrict__ bcnt, int* __restrict__ boff, int* __restrict__ rowoff){
  __shared__ int s[512];
  int t=threadIdx.x;
  int v = (t<NB)? bcnt[t]:0;
  s[t]=v; __syncthreads();
  for(int off=1;off<512;off<<=1){
    int x=(t>=off)?s[t-off]:0;
    __syncthreads();
    s[t]+=x;
    __syncthreads();
  }
  if(t<NB) boff[t]=s[t]-v;
  if(t==0) rowoff[NN]=NE;
}

__global__ void k_prefix(const int* __restrict__ blockcnt, const int* __restrict__ boff,
                         int* __restrict__ pref){
  __shared__ int s[256];
  int k=blockIdx.x, t=threadIdx.x;
  int v = (t<NBLK)? blockcnt[k*256+t] : 0;
  s[t]=v; __syncthreads();
  for(int off=1;off<256;off<<=1){
    int x=(t>=off)?s[t-off]:0;
    __syncthreads();
    s[t]+=x;
    __syncthreads();
  }
  if(t<NBLK) pref[k*256+t] = boff[k] + s[t]-v;
}

__global__ __launch_bounds__(256) void k_bscatter(const int* __restrict__ src, const int* __restrict__ dst,
                                                  const int* __restrict__ pref, unsigned* __restrict__ ebuf){
  __shared__ int cur[NB];
  __shared__ int pb[NB];
  for(int i=threadIdx.x;i<NB;i+=256){ cur[i]=0; pb[i]=pref[i*256+blockIdx.x]; }
  __syncthreads();
  int base=blockIdx.x*CHUNK;
  for(int i=threadIdx.x;i<CHUNK;i+=256){
    int e=base+i;
    if(e<NE){
      int d=dst[e];
      int k=((unsigned)d)>>8;
      int r=atomicAdd(&cur[k],1);
      ebuf[pb[k]+r] = (unsigned)src[e] | ((unsigned)(d&255)<<20);
    }
  }
}

__global__ __launch_bounds__(256) void k_bsort(const unsigned* __restrict__ ebuf, const int* __restrict__ bcnt,
                                               const int* __restrict__ boff, int* __restrict__ rowoff,
                                               float* __restrict__ invd, int* __restrict__ csr){
  __shared__ unsigned el[BCAP];
  __shared__ int dg[256], sc[256], cu[256];
  int b=blockIdx.x, t=threadIdx.x;
  int c = bcnt[b]; if(c>BCAP) c=BCAP;
  int base = boff[b];
  for(int i=t;i<c;i+=256) el[i]=ebuf[base+i];
  dg[t]=0;
  __syncthreads();
  for(int i=t;i<c;i+=256) atomicAdd(&dg[el[i]>>20],1);
  __syncthreads();
  int v = dg[t];
  sc[t]=v; __syncthreads();
  for(int off=1;off<256;off<<=1){
    int x=(t>=off)?sc[t-off]:0;
    __syncthreads();
    sc[t]+=x;
    __syncthreads();
  }
  int excl = sc[t]-v;
  int node = b*256+t;
  if(node<NN){
    rowoff[node]=base+excl;
    invd[node]=1.0f/fmaxf((float)v,1.0f);
  }
  cu[t]=excl;
  __syncthreads();
  for(int i=t;i<c;i+=256){
    unsigned e=el[i];
    int d=e>>20;
    int p=atomicAdd(&cu[d],1);
    csr[base+p] = (int)(e & 0xFFFFFu);
  }
}

// ---------------- input conversion & weight repack ----------------
__global__ void k_cvtin(const float* __restrict__ x, unsigned* __restrict__ xb, int n4){
  int i = blockIdx.x*256+threadIdx.x;
  if(i<n4){
    float4 v = *(const float4*)&x[i*4];
    uint2 p;
    p.x = (unsigned)f2b(v.x) | ((unsigned)f2b(v.y)<<16);
    p.y = (unsigned)f2b(v.z) | ((unsigned)f2b(v.w)<<16);
    *(uint2*)&xb[i*2] = p;
  }
}

// frag-ready: wf[((kcb*8+nt)*64+l)*8+j] = bf16(W[(kcb*32+8*(l>>4)+j)*128 + nt*16+(l&15)])
__global__ void k_repack(const float* __restrict__ W1, const float* __restrict__ W2,
                         const float* __restrict__ Ws, const float* __restrict__ Wn,
                         unsigned short* __restrict__ wf){
  int t = blockIdx.x*256+threadIdx.x;
  if(t >= 122880) return;
  const float* src; int rem;
  if(t < 8192){ src = W1; rem = t; }
  else {
    int u = t - 8192;
    int m = u >> 14; rem = u & 16383;
    if(m==0) src = W2;
    else if(m<=3) src = Ws + (size_t)(m-1)*HH*HH;
    else src = Wn + (size_t)(m-4)*HH*HH;
  }
  int j = rem&7, l=(rem>>3)&63, nt=(rem>>9)&7, kcb=rem>>12;
  int k = kcb*32 + 8*(l>>4) + j;
  int n = nt*16 + (l&15);
  wf[t] = f2b(src[(size_t)k*HH + n]);
}

// ---------------- mean aggregation: fp8 gather, one wave per node, 4 edges/iter ----------------
__global__ __launch_bounds__(256) void k_agg(const uint2* __restrict__ hf8, const int* __restrict__ csr,
                                             const int* __restrict__ rowoff, const float* __restrict__ invd,
                                             uint4* __restrict__ aggb){
  int wave=threadIdx.x>>6, lane=threadIdx.x&63;
  int n = blockIdx.x*4+wave;
  if(n>=NN) return;
  int beg=rowoff[n], end=rowoff[n+1];
  int c = lane&15, q=lane>>4;
  float a0=0.f,a1=0.f,a2=0.f,a3=0.f,a4=0.f,a5=0.f,a6=0.f,a7=0.f;
  int j=beg;
  for(; j+4<=end; j+=4){
    int s0=csr[j+q];
    uint2 u=hf8[(size_t)s0*16+c];
    float d0[4], d1[4];
    f8dec4(u.x,d0); f8dec4(u.y,d1);
    a0+=d0[0]; a1+=d0[1]; a2+=d0[2]; a3+=d0[3];
    a4+=d1[0]; a5+=d1[1]; a6+=d1[2]; a7+=d1[3];
  }
  if(j<end){
    if(j+q<end){
      int s0=csr[j+q];
      uint2 u=hf8[(size_t)s0*16+c];
      float d0[4], d1[4];
      f8dec4(u.x,d0); f8dec4(u.y,d1);
      a0+=d0[0]; a1+=d0[1]; a2+=d0[2]; a3+=d0[3];
      a4+=d1[0]; a5+=d1[1]; a6+=d1[2]; a7+=d1[3];
    }
  }
  a0+=__shfl_xor(a0,16); a1+=__shfl_xor(a1,16); a2+=__shfl_xor(a2,16); a3+=__shfl_xor(a3,16);
  a4+=__shfl_xor(a4,16); a5+=__shfl_xor(a5,16); a6+=__shfl_xor(a6,16); a7+=__shfl_xor(a7,16);
  a0+=__shfl_xor(a0,32); a1+=__shfl_xor(a1,32); a2+=__shfl_xor(a2,32); a3+=__shfl_xor(a3,32);
  a4+=__shfl_xor(a4,32); a5+=__shfl_xor(a5,32); a6+=__shfl_xor(a6,32); a7+=__shfl_xor(a7,32);
  if(q==0){
    float s=invd[n];
    uint4 p;
    p.x = (unsigned)f2b(a0*s) | ((unsigned)f2b(a1*s)<<16);
    p.y = (unsigned)f2b(a2*s) | ((unsigned)f2b(a3*s)<<16);
    p.z = (unsigned)f2b(a4*s) | ((unsigned)f2b(a5*s)<<16);
    p.w = (unsigned)f2b(a6*s) | ((unsigned)f2b(a7*s)<<16);
    aggb[(size_t)n*16 + c] = p;
  }
}

// ---------------- MFMA GEMM: out = [LN](act(A@W [+ A2@W2] + b)) ----------------
// MEAN=1: skip out/hf8 writes, accumulate column sums into gsum instead.
template<int K, int DUAL, int RELU, int LN, int F8, int MEAN>
__global__ __launch_bounds__(256) void k_mfma(
    const unsigned short* __restrict__ A, const unsigned short* __restrict__ A2,
    const unsigned short* __restrict__ Wf, const unsigned short* __restrict__ Wf2,
    const float* __restrict__ bias, const float* __restrict__ lng, const float* __restrict__ lnb,
    unsigned short* __restrict__ out, unsigned char* __restrict__ hf8, float* __restrict__ gsum)
{
  constexpr int KC = K/32;
  __shared__ unsigned short Wl[KC*8*64*8];
  __shared__ unsigned short Wl2[DUAL ? KC*8*64*8 : 8];
  __shared__ float sm[MEAN ? 4*128 : 4];
  int tid = threadIdx.x;
  {
    const int tot = KC*8*64*8/8;
    for(int i=tid;i<tot;i+=256){
      ((uint4*)Wl)[i] = ((const uint4*)Wf)[i];
      if(DUAL) ((uint4*)Wl2)[i] = ((const uint4*)Wf2)[i];
    }
  }
  __syncthreads();
  int l = tid&63, wv = tid>>6;
  int grp = l>>4, lc = l&15;
  int node0 = blockIdx.x*64 + wv*16;
  int arow = node0 + lc; if(arow > NN-1) arow = NN-1;
  f32x4 acc[8] = {};
  const s8v* Wv  = (const s8v*)Wl;
  const s8v* Wv2 = (const s8v*)Wl2;
  #pragma unroll
  for(int kcb=0;kcb<KC;kcb++){
    s8v a = *(const s8v*)&A[(size_t)arow*K + kcb*32 + 8*grp];
    s8v a2;
    if(DUAL) a2 = *(const s8v*)&A2[(size_t)arow*K + kcb*32 + 8*grp];
    #pragma unroll
    for(int nt=0;nt<8;nt++){
      acc[nt] = __builtin_amdgcn_mfma_f32_16x16x32_bf16(a, Wv[(kcb*8+nt)*64 + l], acc[nt], 0,0,0);
      if(DUAL)
        acc[nt] = __builtin_amdgcn_mfma_f32_16x16x32_bf16(a2, Wv2[(kcb*8+nt)*64 + l], acc[nt], 0,0,0);
    }
  }
  float bc[8], gc[8], oc[8];
  #pragma unroll
  for(int nt=0;nt<8;nt++){
    bc[nt] = bias[nt*16+lc];
    if(LN){ gc[nt]=lng[nt*16+lc]; oc[nt]=lnb[nt*16+lc]; }
  }
  float msum[8];
  #pragma unroll
  for(int nt=0;nt<8;nt++) msum[nt]=0.f;
  #pragma unroll
  for(int r=0;r<4;r++){
    float x[8]; float s=0.f, ss=0.f;
    #pragma unroll
    for(int nt=0;nt<8;nt++){
      float v = acc[nt][r] + bc[nt];
      if(RELU) v = fmaxf(v, 0.f);
      x[nt]=v; s+=v; ss+=v*v;
    }
    if(LN){
      #pragma unroll
      for(int m=1;m<=8;m<<=1){ s+=__shfl_xor(s,m); ss+=__shfl_xor(ss,m); }
      float mu = s*(1.0f/HH);
      float var = ss*(1.0f/HH) - mu*mu;
      float rs = rsqrtf(var + LNEPS);
      #pragma unroll
      for(int nt=0;nt<8;nt++) x[nt] = gc[nt]*(x[nt]-mu)*rs + oc[nt];
    }
    int node = node0 + grp*4 + r;
    if(node<NN){
      if(MEAN){
        #pragma unroll
        for(int nt=0;nt<8;nt++) msum[nt]+=x[nt];
      } else {
        #pragma unroll
        for(int nt=0;nt<8;nt++) out[(size_t)node*HH + nt*16 + lc] = f2b(x[nt]);
        if(F8){
          #pragma unroll
          for(int nt=0;nt<8;nt++) hf8[(size_t)node*HH + nt*16 + lc] = f8enc(x[nt]);
        }
      }
    }
  }
  if(MEAN){
    #pragma unroll
    for(int nt=0;nt<8;nt++){
      msum[nt]+=__shfl_xor(msum[nt],16);
      msum[nt]+=__shfl_xor(msum[nt],32);
    }
    if(grp==0){
      #pragma unroll
      for(int nt=0;nt<8;nt++) sm[wv*128 + nt*16 + lc] = msum[nt];
    }
    __syncthreads();
    if(tid<128){
      float v = sm[tid] + sm[128+tid] + sm[256+tid] + sm[384+tid];
      atomicAdd(&gsum[tid], v);
    }
  }
}

// ---------------- output head ----------------
__global__ void k_out(const float* __restrict__ g, const float* __restrict__ Wout,
                      const float* __restrict__ bout, float* __restrict__ out){
  int o=threadIdx.x;
  if(o<OO){
    float acc=bout[o];
    for(int k=0;k<HH;k++) acc = fmaf(g[k]*(1.0f/NN), Wout[k*OO+o], acc);
    out[o]=acc;
  }
}

extern "C" void kernel_launch(void* const* d_in, const int* in_sizes, int n_in,
                              void* d_out, int out_size, void* d_ws, size_t ws_size,
                              hipStream_t stream){
  const float* nodes = (const float*)d_in[0];
  const int*   src   = (const int*)d_in[1];
  const int*   dst   = (const int*)d_in[2];
  const float* W_in1 = (const float*)d_in[3];
  const float* b_in1 = (const float*)d_in[4];
  const float* W_in2 = (const float*)d_in[5];
  const float* b_in2 = (const float*)d_in[6];
  const float* W_self  = (const float*)d_in[7];
  const float* W_neigh = (const float*)d_in[8];
  const float* b_sage  = (const float*)d_in[9];
  const float* ln_g    = (const float*)d_in[10];
  const float* ln_b    = (const float*)d_in[11];
  const float* W_out   = (const float*)d_in[12];
  const float* b_out   = (const float*)d_in[13];

  char* w=(char*)d_ws;
  unsigned short* hb   = (unsigned short*)w; w += (size_t)NN*HH*2;   // 25.6 MB
  unsigned short* aggb = (unsigned short*)w; w += (size_t)NN*HH*2;   // 25.6 MB
  unsigned short* xb   = (unsigned short*)w; w += (size_t)NN*FF*2;   // 12.8 MB
  unsigned char*  hf8  = (unsigned char*)w;  w += (size_t)NN*HH;     // 12.8 MB fp8 shadow
  unsigned short* wf   = (unsigned short*)w; w += (size_t)122880*2;
  unsigned* ebuf = (unsigned*)w; w += (size_t)NE*4;                  // 6.4 MB
  int* csr    = (int*)w;   w += (size_t)NE*4;                        // 6.4 MB
  int* rowoff = (int*)w;   w += (size_t)(NN+8)*4;
  float* invd = (float*)w; w += (size_t)NN*4;
  int* bcnt   = (int*)w;   w += (size_t)(NB+1)*4;
  int* boff   = (int*)w;   w += (size_t)(NB+1)*4;
  int* blockcnt=(int*)w;   w += (size_t)NB*256*4;
  int* pref   = (int*)w;   w += (size_t)NB*256*4;
  float* gsum = (float*)w; w += 128*4;

  hipMemsetAsync(bcnt, 0, (size_t)(NB+1)*4, stream);
  hipMemsetAsync(gsum, 0, 128*4, stream);

  k_bcount<<<NBLK,256,0,stream>>>(dst,bcnt,blockcnt);
  k_bscan<<<1,512,0,stream>>>(bcnt,boff,rowoff);
  k_prefix<<<NB,256,0,stream>>>(blockcnt,boff,pref);
  k_bscatter<<<NBLK,256,0,stream>>>(src,dst,pref,ebuf);
  k_bsort<<<NB,256,0,stream>>>(ebuf,bcnt,boff,rowoff,invd,csr);

  k_cvtin<<<((NN*FF/4)+255)/256,256,0,stream>>>(nodes,(unsigned*)xb, NN*FF/4);
  k_repack<<<(122880+255)/256,256,0,stream>>>(W_in1,W_in2,W_self,W_neigh,wf);

  const int GB = (NN+63)/64;
  // input MLP
  k_mfma<FF,0,1,0,0,0><<<GB,256,0,stream>>>(xb,nullptr, wf, nullptr, b_in1,nullptr,nullptr, aggb, nullptr, nullptr);
  k_mfma<HH,0,0,0,1,0><<<GB,256,0,stream>>>(aggb,nullptr, wf+8192, nullptr, b_in2,nullptr,nullptr, hb, hf8, nullptr);

  for(int l=0;l<NL;l++){
    k_agg<<<(NN+3)/4,256,0,stream>>>((const uint2*)hf8,csr,rowoff,invd,(uint4*)aggb);
    if(l<NL-1)
      k_mfma<HH,1,1,1,1,0><<<GB,256,0,stream>>>(hb, aggb,
          wf+24576+(size_t)l*16384, wf+73728+(size_t)l*16384,
          b_sage+(size_t)l*HH, ln_g+(size_t)l*HH, ln_b+(size_t)l*HH, hb, hf8, nullptr);
    else
      k_mfma<HH,1,1,1,0,1><<<GB,256,0,stream>>>(hb, aggb,
          wf+24576+(size_t)l*16384, wf+73728+(size_t)l*16384,
          b_sage+(size_t)l*HH, ln_g+(size_t)l*HH, ln_b+(size_t)l*HH, hb, nullptr, gsum);
  }
  k_out<<<1,64,0,stream>>>(gsum,W_out,b_out,(float*)d_out);
}

// Round 7
// 400.487 us; speedup vs baseline: 3.5657x; 1.0092x over previous
//
#include <hip/hip_runtime.h>
#include <hip/hip_bf16.h>

#define NN 100000
#define NE 1600000
#define FF 64
#define HH 128
#define OO 10
#define NL 3
#define NB 391
#define NBLK 250
#define CHUNK 6400
#define BCAP 5376
#define LNEPS 1e-5f

typedef short s8v __attribute__((ext_vector_type(8)));   // 8 bf16 = 4 VGPR
typedef float f32x4 __attribute__((ext_vector_type(4)));
typedef float f32x2 __attribute__((ext_vector_type(2)));

__device__ __forceinline__ unsigned short f2b(float f){
  unsigned u = __float_as_uint(f);
  unsigned r = (u + 0x7FFFu + ((u>>16)&1u)) >> 16;
  return (unsigned short)r;
}
__device__ __forceinline__ float b2f(unsigned short b){
  return __uint_as_float(((unsigned)b)<<16);
}

#if __has_builtin(__builtin_amdgcn_cvt_pk_f32_fp8) && __has_builtin(__builtin_amdgcn_cvt_pk_fp8_f32)
__device__ __forceinline__ unsigned char f8enc(float x){
  int p = __builtin_amdgcn_cvt_pk_fp8_f32(x, x, 0, false);
  return (unsigned char)(p & 0xFF);
}
__device__ __forceinline__ void f8dec4(unsigned u, float* o){
  f32x2 lo = __builtin_amdgcn_cvt_pk_f32_fp8(u, false);
  f32x2 hi = __builtin_amdgcn_cvt_pk_f32_fp8(u, true);
  o[0]=lo[0]; o[1]=lo[1]; o[2]=hi[0]; o[3]=hi[1];
}
#else
#include <hip/hip_fp8.h>
__device__ __forceinline__ unsigned char f8enc(float x){
  __hip_fp8_e4m3 q(x); return (unsigned char)q.__x;
}
__device__ __forceinline__ void f8dec4(unsigned u, float* o){
  for(int i=0;i<4;i++){
    __hip_fp8_e4m3 q; q.__x = (unsigned char)(u>>(8*i));
    o[i] = (float)q;
  }
}
#endif

// ---------------- bucketed CSR build (contention-free radix) ----------------
__global__ __launch_bounds__(256) void k_bcount(const int* __restrict__ dst, int* __restrict__ bcnt,
                                                int* __restrict__ blockcnt){
  __shared__ int h[NB];
  for(int i=threadIdx.x;i<NB;i+=256) h[i]=0;
  __syncthreads();
  int base = blockIdx.x*CHUNK;
  for(int i=threadIdx.x;i<CHUNK;i+=256){
    int e = base+i;
    if(e<NE) atomicAdd(&h[((unsigned)dst[e])>>8],1);
  }
  __syncthreads();
  for(int i=threadIdx.x;i<NB;i+=256){
    int v=h[i];
    blockcnt[i*256 + blockIdx.x] = v;
    if(v) atomicAdd(&bcnt[i],v);
  }
}

__global__ void k_bscan(const int* __restrict__ bcnt, int* __restrict__ boff, int* __restrict__ rowoff){
  __shared__ int s[512];
  int t=threadIdx.x;
  int v = (t<NB)? bcnt[t]:0;
  s[t]=v; __syncthreads();
  for(int off=1;off<512;off<<=1){
    int x=(t>=off)?s[t-off]:0;
    __syncthreads();
    s[t]+=x;
    __syncthreads();
  }
  if(t<NB) boff[t]=s[t]-v;
  if(t==0) rowoff[NN]=NE;
}

__global__ void k_prefix(const int* __restrict__ blockcnt, const int* __restrict__ boff,
                         int* __restrict__ pref){
  __shared__ int s[256];
  int k=blockIdx.x, t=threadIdx.x;
  int v = (t<NBLK)? blockcnt[k*256+t] : 0;
  s[t]=v; __syncthreads();
  for(int off=1;off<256;off<<=1){
    int x=(t>=off)?s[t-off]:0;
    __syncthreads();
    s[t]+=x;
    __syncthreads();
  }
  if(t<NBLK) pref[k*256+t] = boff[k] + s[t]-v;
}

__global__ __launch_bounds__(256) void k_bscatter(const int* __restrict__ src, const int* __restrict__ dst,
                                                  const int* __restrict__ pref, unsigned* __restrict__ ebuf){
  __shared__ int cur[NB];
  __shared__ int pb[NB];
  for(int i=threadIdx.x;i<NB;i+=256){ cur[i]=0; pb[i]=pref[i*256+blockIdx.x]; }
  __syncthreads();
  int base=blockIdx.x*CHUNK;
  for(int i=threadIdx.x;i<CHUNK;i+=256){
    int e=base+i;
    if(e<NE){
      int d=dst[e];
      int k=((unsigned)d)>>8;
      int r=atomicAdd(&cur[k],1);
      ebuf[pb[k]+r] = (unsigned)src[e] | ((unsigned)(d&255)<<20);
    }
  }
}

__global__ __launch_bounds__(256) void k_bsort(const unsigned* __restrict__ ebuf, const int* __restrict__ bcnt,
                                               const int* __restrict__ boff, int* __restrict__ rowoff,
                                               float* __restrict__ invd, int* __restrict__ csr){
  __shared__ unsigned el[BCAP];
  __shared__ int dg[256], sc[256], cu[256];
  int b=blockIdx.x, t=threadIdx.x;
  int c = bcnt[b]; if(c>BCAP) c=BCAP;
  int base = boff[b];
  for(int i=t;i<c;i+=256) el[i]=ebuf[base+i];
  dg[t]=0;
  __syncthreads();
  for(int i=t;i<c;i+=256) atomicAdd(&dg[el[i]>>20],1);
  __syncthreads();
  int v = dg[t];
  sc[t]=v; __syncthreads();
  for(int off=1;off<256;off<<=1){
    int x=(t>=off)?sc[t-off]:0;
    __syncthreads();
    sc[t]+=x;
    __syncthreads();
  }
  int excl = sc[t]-v;
  int node = b*256+t;
  if(node<NN){
    rowoff[node]=base+excl;
    invd[node]=1.0f/fmaxf((float)v,1.0f);
  }
  cu[t]=excl;
  __syncthreads();
  for(int i=t;i<c;i+=256){
    unsigned e=el[i];
    int d=e>>20;
    int p=atomicAdd(&cu[d],1);
    csr[base+p] = (int)(e & 0xFFFFFu);
  }
}

// ---------------- input conversion & weight repack ----------------
__global__ void k_cvtin(const float* __restrict__ x, unsigned* __restrict__ xb, int n4){
  int i = blockIdx.x*256+threadIdx.x;
  if(i<n4){
    float4 v = *(const float4*)&x[i*4];
    uint2 p;
    p.x = (unsigned)f2b(v.x) | ((unsigned)f2b(v.y)<<16);
    p.y = (unsigned)f2b(v.z) | ((unsigned)f2b(v.w)<<16);
    *(uint2*)&xb[i*2] = p;
  }
}

// frag-ready: wf[((kcb*8+nt)*64+l)*8+j] = bf16(W[(kcb*32+8*(l>>4)+j)*128 + nt*16+(l&15)])
__global__ void k_repack(const float* __restrict__ W1, const float* __restrict__ W2,
                         const float* __restrict__ Ws, const float* __restrict__ Wn,
                         unsigned short* __restrict__ wf){
  int t = blockIdx.x*256+threadIdx.x;
  if(t >= 122880) return;
  const float* src; int rem;
  if(t < 8192){ src = W1; rem = t; }
  else {
    int u = t - 8192;
    int m = u >> 14; rem = u & 16383;
    if(m==0) src = W2;
    else if(m<=3) src = Ws + (size_t)(m-1)*HH*HH;
    else src = Wn + (size_t)(m-4)*HH*HH;
  }
  int j = rem&7, l=(rem>>3)&63, nt=(rem>>9)&7, kcb=rem>>12;
  int k = kcb*32 + 8*(l>>4) + j;
  int n = nt*16 + (l&15);
  wf[t] = f2b(src[(size_t)k*HH + n]);
}

// ---------------- mean aggregation: fp8 gather, one wave per node, 4 edges/iter ----------------
__global__ __launch_bounds__(256) void k_agg(const uint2* __restrict__ hf8, const int* __restrict__ csr,
                                             const int* __restrict__ rowoff, const float* __restrict__ invd,
                                             uint4* __restrict__ aggb){
  int wave=threadIdx.x>>6, lane=threadIdx.x&63;
  int n = blockIdx.x*4+wave;
  if(n>=NN) return;
  int beg=rowoff[n], end=rowoff[n+1];
  int c = lane&15, q=lane>>4;
  float a0=0.f,a1=0.f,a2=0.f,a3=0.f,a4=0.f,a5=0.f,a6=0.f,a7=0.f;
  int j=beg;
  for(; j+4<=end; j+=4){
    int s0=csr[j+q];
    uint2 u=hf8[(size_t)s0*16+c];
    float d0[4], d1[4];
    f8dec4(u.x,d0); f8dec4(u.y,d1);
    a0+=d0[0]; a1+=d0[1]; a2+=d0[2]; a3+=d0[3];
    a4+=d1[0]; a5+=d1[1]; a6+=d1[2]; a7+=d1[3];
  }
  if(j<end){
    if(j+q<end){
      int s0=csr[j+q];
      uint2 u=hf8[(size_t)s0*16+c];
      float d0[4], d1[4];
      f8dec4(u.x,d0); f8dec4(u.y,d1);
      a0+=d0[0]; a1+=d0[1]; a2+=d0[2]; a3+=d0[3];
      a4+=d1[0]; a5+=d1[1]; a6+=d1[2]; a7+=d1[3];
    }
  }
  a0+=__shfl_xor(a0,16); a1+=__shfl_xor(a1,16); a2+=__shfl_xor(a2,16); a3+=__shfl_xor(a3,16);
  a4+=__shfl_xor(a4,16); a5+=__shfl_xor(a5,16); a6+=__shfl_xor(a6,16); a7+=__shfl_xor(a7,16);
  a0+=__shfl_xor(a0,32); a1+=__shfl_xor(a1,32); a2+=__shfl_xor(a2,32); a3+=__shfl_xor(a3,32);
  a4+=__shfl_xor(a4,32); a5+=__shfl_xor(a5,32); a6+=__shfl_xor(a6,32); a7+=__shfl_xor(a7,32);
  if(q==0){
    float s=invd[n];
    uint4 p;
    p.x = (unsigned)f2b(a0*s) | ((unsigned)f2b(a1*s)<<16);
    p.y = (unsigned)f2b(a2*s) | ((unsigned)f2b(a3*s)<<16);
    p.z = (unsigned)f2b(a4*s) | ((unsigned)f2b(a5*s)<<16);
    p.w = (unsigned)f2b(a6*s) | ((unsigned)f2b(a7*s)<<16);
    aggb[(size_t)n*16 + c] = p;
  }
}

// ---------------- MFMA GEMM: 128 rows/block, B-fragments direct from L2 ----------------
// MEAN=1: skip out/hf8 writes, accumulate column sums into gsum instead.
template<int K, int DUAL, int RELU, int LN, int F8, int MEAN>
__global__ __launch_bounds__(256) void k_mfma(
    const unsigned short* __restrict__ A, const unsigned short* __restrict__ A2,
    const unsigned short* __restrict__ Wf, const unsigned short* __restrict__ Wf2,
    const float* __restrict__ bias, const float* __restrict__ lng, const float* __restrict__ lnb,
    unsigned short* __restrict__ out, unsigned char* __restrict__ hf8, float* __restrict__ gsum)
{
  constexpr int KC = K/32;
  __shared__ float sm[MEAN ? 4*128 : 4];
  int tid = threadIdx.x;
  int l = tid&63, wv = tid>>6;
  int grp = l>>4, lc = l&15;
  int node0 = blockIdx.x*128;
  const s8v* __restrict__ Wv  = (const s8v*)Wf;
  const s8v* __restrict__ Wv2 = (const s8v*)Wf2;
  f32x4 acc[2][8] = {};
  int r0 = node0 + wv*16 + lc;      if(r0>NN-1) r0=NN-1;
  int r1 = node0 + 64 + wv*16 + lc; if(r1>NN-1) r1=NN-1;
  #pragma unroll
  for(int kcb=0;kcb<KC;kcb++){
    s8v a0 = *(const s8v*)&A[(size_t)r0*K + kcb*32 + 8*grp];
    s8v a1 = *(const s8v*)&A[(size_t)r1*K + kcb*32 + 8*grp];
    s8v c0, c1;
    if(DUAL){
      c0 = *(const s8v*)&A2[(size_t)r0*K + kcb*32 + 8*grp];
      c1 = *(const s8v*)&A2[(size_t)r1*K + kcb*32 + 8*grp];
    }
    #pragma unroll
    for(int nt=0;nt<8;nt++){
      s8v b = Wv[(kcb*8+nt)*64 + l];
      acc[0][nt] = __builtin_amdgcn_mfma_f32_16x16x32_bf16(a0, b, acc[0][nt], 0,0,0);
      acc[1][nt] = __builtin_amdgcn_mfma_f32_16x16x32_bf16(a1, b, acc[1][nt], 0,0,0);
      if(DUAL){
        s8v b2 = Wv2[(kcb*8+nt)*64 + l];
        acc[0][nt] = __builtin_amdgcn_mfma_f32_16x16x32_bf16(c0, b2, acc[0][nt], 0,0,0);
        acc[1][nt] = __builtin_amdgcn_mfma_f32_16x16x32_bf16(c1, b2, acc[1][nt], 0,0,0);
      }
    }
  }
  float bc[8], gc[8], oc[8];
  #pragma unroll
  for(int nt=0;nt<8;nt++){
    bc[nt] = bias[nt*16+lc];
    if(LN){ gc[nt]=lng[nt*16+lc]; oc[nt]=lnb[nt*16+lc]; }
  }
  float msum[8];
  #pragma unroll
  for(int nt=0;nt<8;nt++) msum[nt]=0.f;
  #pragma unroll
  for(int s2=0;s2<2;s2++){
    #pragma unroll
    for(int r=0;r<4;r++){
      float x[8]; float s=0.f, ss=0.f;
      #pragma unroll
      for(int nt=0;nt<8;nt++){
        float v = acc[s2][nt][r] + bc[nt];
        if(RELU) v = fmaxf(v, 0.f);
        x[nt]=v; s+=v; ss+=v*v;
      }
      if(LN){
        #pragma unroll
        for(int m=1;m<=8;m<<=1){ s+=__shfl_xor(s,m); ss+=__shfl_xor(ss,m); }
        float mu = s*(1.0f/HH);
        float var = ss*(1.0f/HH) - mu*mu;
        float rs = rsqrtf(var + LNEPS);
        #pragma unroll
        for(int nt=0;nt<8;nt++) x[nt] = gc[nt]*(x[nt]-mu)*rs + oc[nt];
      }
      int node = node0 + s2*64 + wv*16 + grp*4 + r;
      if(node<NN){
        if(MEAN){
          #pragma unroll
          for(int nt=0;nt<8;nt++) msum[nt]+=x[nt];
        } else {
          #pragma unroll
          for(int nt=0;nt<8;nt++) out[(size_t)node*HH + nt*16 + lc] = f2b(x[nt]);
          if(F8){
            #pragma unroll
            for(int nt=0;nt<8;nt++) hf8[(size_t)node*HH + nt*16 + lc] = f8enc(x[nt]);
          }
        }
      }
    }
  }
  if(MEAN){
    #pragma unroll
    for(int nt=0;nt<8;nt++){
      msum[nt]+=__shfl_xor(msum[nt],16);
      msum[nt]+=__shfl_xor(msum[nt],32);
    }
    if(grp==0){
      #pragma unroll
      for(int nt=0;nt<8;nt++) sm[wv*128 + nt*16 + lc] = msum[nt];
    }
    __syncthreads();
    if(tid<128){
      float v = sm[tid] + sm[128+tid] + sm[256+tid] + sm[384+tid];
      atomicAdd(&gsum[tid], v);
    }
  }
}

// ---------------- output head ----------------
__global__ void k_out(const float* __restrict__ g, const float* __restrict__ Wout,
                      const float* __restrict__ bout, float* __restrict__ out){
  int o=threadIdx.x;
  if(o<OO){
    float acc=bout[o];
    for(int k=0;k<HH;k++) acc = fmaf(g[k]*(1.0f/NN), Wout[k*OO+o], acc);
    out[o]=acc;
  }
}

extern "C" void kernel_launch(void* const* d_in, const int* in_sizes, int n_in,
                              void* d_out, int out_size, void* d_ws, size_t ws_size,
                              hipStream_t stream){
  const float* nodes = (const float*)d_in[0];
  const int*   src   = (const int*)d_in[1];
  const int*   dst   = (const int*)d_in[2];
  const float* W_in1 = (const float*)d_in[3];
  const float* b_in1 = (const float*)d_in[4];
  const float* W_in2 = (const float*)d_in[5];
  const float* b_in2 = (const float*)d_in[6];
  const float* W_self  = (const float*)d_in[7];
  const float* W_neigh = (const float*)d_in[8];
  const float* b_sage  = (const float*)d_in[9];
  const float* ln_g    = (const float*)d_in[10];
  const float* ln_b    = (const float*)d_in[11];
  const float* W_out   = (const float*)d_in[12];
  const float* b_out   = (const float*)d_in[13];

  char* w=(char*)d_ws;
  unsigned short* hb   = (unsigned short*)w; w += (size_t)NN*HH*2;   // 25.6 MB
  unsigned short* aggb = (unsigned short*)w; w += (size_t)NN*HH*2;   // 25.6 MB
  unsigned short* xb   = (unsigned short*)w; w += (size_t)NN*FF*2;   // 12.8 MB
  unsigned char*  hf8  = (unsigned char*)w;  w += (size_t)NN*HH;     // 12.8 MB fp8 shadow
  unsigned short* wf   = (unsigned short*)w; w += (size_t)122880*2;
  unsigned* ebuf = (unsigned*)w; w += (size_t)NE*4;                  // 6.4 MB
  int* csr    = (int*)w;   w += (size_t)NE*4;                        // 6.4 MB
  int* rowoff = (int*)w;   w += (size_t)(NN+8)*4;
  float* invd = (float*)w; w += (size_t)NN*4;
  int* bcnt   = (int*)w;   w += (size_t)(NB+1)*4;
  int* boff   = (int*)w;   w += (size_t)(NB+1)*4;
  int* blockcnt=(int*)w;   w += (size_t)NB*256*4;
  int* pref   = (int*)w;   w += (size_t)NB*256*4;
  float* gsum = (float*)w; w += 128*4;

  hipMemsetAsync(bcnt, 0, (size_t)(NB+1)*4, stream);
  hipMemsetAsync(gsum, 0, 128*4, stream);

  k_bcount<<<NBLK,256,0,stream>>>(dst,bcnt,blockcnt);
  k_bscan<<<1,512,0,stream>>>(bcnt,boff,rowoff);
  k_prefix<<<NB,256,0,stream>>>(blockcnt,boff,pref);
  k_bscatter<<<NBLK,256,0,stream>>>(src,dst,pref,ebuf);
  k_bsort<<<NB,256,0,stream>>>(ebuf,bcnt,boff,rowoff,invd,csr);

  k_cvtin<<<((NN*FF/4)+255)/256,256,0,stream>>>(nodes,(unsigned*)xb, NN*FF/4);
  k_repack<<<(122880+255)/256,256,0,stream>>>(W_in1,W_in2,W_self,W_neigh,wf);

  const int GB2 = (NN+127)/128;
  // input MLP
  k_mfma<FF,0,1,0,0,0><<<GB2,256,0,stream>>>(xb,nullptr, wf, nullptr, b_in1,nullptr,nullptr, aggb, nullptr, nullptr);
  k_mfma<HH,0,0,0,1,0><<<GB2,256,0,stream>>>(aggb,nullptr, wf+8192, nullptr, b_in2,nullptr,nullptr, hb, hf8, nullptr);

  for(int l=0;l<NL;l++){
    k_agg<<<(NN+3)/4,256,0,stream>>>((const uint2*)hf8,csr,rowoff,invd,(uint4*)aggb);
    if(l<NL-1)
      k_mfma<HH,1,1,1,1,0><<<GB2,256,0,stream>>>(hb, aggb,
          wf+24576+(size_t)l*16384, wf+73728+(size_t)l*16384,
          b_sage+(size_t)l*HH, ln_g+(size_t)l*HH, ln_b+(size_t)l*HH, hb, hf8, nullptr);
    else
      k_mfma<HH,1,1,1,0,1><<<GB2,256,0,stream>>>(hb, aggb,
          wf+24576+(size_t)l*16384, wf+73728+(size_t)l*16384,
          b_sage+(size_t)l*HH, ln_g+(size_t)l*HH, ln_b+(size_t)l*HH, hb, nullptr, gsum);
  }
  k_out<<<1,64,0,stream>>>(gsum,W_out,b_out,(float*)d_out);
}

// Round 8
// 390.315 us; speedup vs baseline: 3.6586x; 1.0261x over previous
//
#include <hip/hip_runtime.h>
#include <hip/hip_bf16.h>

#define NN 100000
#define NE 1600000
#define FF 64
#define HH 128
#define OO 10
#define NL 3
#define NB 391
#define NBLK 250
#define CHUNK 6400
#define BCAP 5376
#define LNEPS 1e-5f

typedef short s8v __attribute__((ext_vector_type(8)));   // 8 bf16 = 4 VGPR
typedef float f32x4 __attribute__((ext_vector_type(4)));
typedef float f32x2 __attribute__((ext_vector_type(2)));

__device__ __forceinline__ unsigned short f2b(float f){
  unsigned u = __float_as_uint(f);
  unsigned r = (u + 0x7FFFu + ((u>>16)&1u)) >> 16;
  return (unsigned short)r;
}
__device__ __forceinline__ float b2f(unsigned short b){
  return __uint_as_float(((unsigned)b)<<16);
}

#if __has_builtin(__builtin_amdgcn_cvt_pk_f32_fp8) && __has_builtin(__builtin_amdgcn_cvt_pk_fp8_f32)
__device__ __forceinline__ unsigned char f8enc(float x){
  int p = __builtin_amdgcn_cvt_pk_fp8_f32(x, x, 0, false);
  return (unsigned char)(p & 0xFF);
}
__device__ __forceinline__ void f8dec4(unsigned u, float* o){
  f32x2 lo = __builtin_amdgcn_cvt_pk_f32_fp8(u, false);
  f32x2 hi = __builtin_amdgcn_cvt_pk_f32_fp8(u, true);
  o[0]=lo[0]; o[1]=lo[1]; o[2]=hi[0]; o[3]=hi[1];
}
#else
#include <hip/hip_fp8.h>
__device__ __forceinline__ unsigned char f8enc(float x){
  __hip_fp8_e4m3 q(x); return (unsigned char)q.__x;
}
__device__ __forceinline__ void f8dec4(unsigned u, float* o){
  for(int i=0;i<4;i++){
    __hip_fp8_e4m3 q; q.__x = (unsigned char)(u>>(8*i));
    o[i] = (float)q;
  }
}
#endif

// ---------------- bucketed CSR build (contention-free radix) ----------------
__global__ __launch_bounds__(256) void k_bcount(const int* __restrict__ dst, int* __restrict__ bcnt,
                                                int* __restrict__ blockcnt){
  __shared__ int h[NB];
  for(int i=threadIdx.x;i<NB;i+=256) h[i]=0;
  __syncthreads();
  int base = blockIdx.x*CHUNK;
  for(int i=threadIdx.x;i<CHUNK;i+=256){
    int e = base+i;
    if(e<NE) atomicAdd(&h[((unsigned)dst[e])>>8],1);
  }
  __syncthreads();
  for(int i=threadIdx.x;i<NB;i+=256){
    int v=h[i];
    blockcnt[i*256 + blockIdx.x] = v;
    if(v) atomicAdd(&bcnt[i],v);
  }
}

__global__ void k_bscan(const int* __restrict__ bcnt, int* __restrict__ boff, int* __restrict__ rowoff){
  __shared__ int s[512];
  int t=threadIdx.x;
  int v = (t<NB)? bcnt[t]:0;
  s[t]=v; __syncthreads();
  for(int off=1;off<512;off<<=1){
    int x=(t>=off)?s[t-off]:0;
    __syncthreads();
    s[t]+=x;
    __syncthreads();
  }
  if(t<NB) boff[t]=s[t]-v;
  if(t==0) rowoff[NN]=NE;
}

__global__ void k_prefix(const int* __restrict__ blockcnt, const int* __restrict__ boff,
                         int* __restrict__ pref){
  __shared__ int s[256];
  int k=blockIdx.x, t=threadIdx.x;
  int v = (t<NBLK)? blockcnt[k*256+t] : 0;
  s[t]=v; __syncthreads();
  for(int off=1;off<256;off<<=1){
    int x=(t>=off)?s[t-off]:0;
    __syncthreads();
    s[t]+=x;
    __syncthreads();
  }
  if(t<NBLK) pref[k*256+t] = boff[k] + s[t]-v;
}

__global__ __launch_bounds__(256) void k_bscatter(const int* __restrict__ src, const int* __restrict__ dst,
                                                  const int* __restrict__ pref, unsigned* __restrict__ ebuf){
  __shared__ int cur[NB];
  __shared__ int pb[NB];
  for(int i=threadIdx.x;i<NB;i+=256){ cur[i]=0; pb[i]=pref[i*256+blockIdx.x]; }
  __syncthreads();
  int base=blockIdx.x*CHUNK;
  for(int i=threadIdx.x;i<CHUNK;i+=256){
    int e=base+i;
    if(e<NE){
      int d=dst[e];
      int k=((unsigned)d)>>8;
      int r=atomicAdd(&cur[k],1);
      ebuf[pb[k]+r] = (unsigned)src[e] | ((unsigned)(d&255)<<20);
    }
  }
}

__global__ __launch_bounds__(256) void k_bsort(const unsigned* __restrict__ ebuf, const int* __restrict__ bcnt,
                                               const int* __restrict__ boff, int* __restrict__ rowoff,
                                               float* __restrict__ invd, int* __restrict__ csr){
  __shared__ unsigned el[BCAP];
  __shared__ int dg[256], sc[256], cu[256];
  int b=blockIdx.x, t=threadIdx.x;
  int c = bcnt[b]; if(c>BCAP) c=BCAP;
  int base = boff[b];
  for(int i=t;i<c;i+=256) el[i]=ebuf[base+i];
  dg[t]=0;
  __syncthreads();
  for(int i=t;i<c;i+=256) atomicAdd(&dg[el[i]>>20],1);
  __syncthreads();
  int v = dg[t];
  sc[t]=v; __syncthreads();
  for(int off=1;off<256;off<<=1){
    int x=(t>=off)?sc[t-off]:0;
    __syncthreads();
    sc[t]+=x;
    __syncthreads();
  }
  int excl = sc[t]-v;
  int node = b*256+t;
  if(node<NN){
    rowoff[node]=base+excl;
    invd[node]=1.0f/fmaxf((float)v,1.0f);
  }
  cu[t]=excl;
  __syncthreads();
  for(int i=t;i<c;i+=256){
    unsigned e=el[i];
    int d=e>>20;
    int p=atomicAdd(&cu[d],1);
    csr[base+p] = (int)(e & 0xFFFFFu);
  }
}

// ---------------- input conversion & weight repack ----------------
__global__ void k_cvtin(const float* __restrict__ x, unsigned* __restrict__ xb, int n4){
  int i = blockIdx.x*256+threadIdx.x;
  if(i<n4){
    float4 v = *(const float4*)&x[i*4];
    uint2 p;
    p.x = (unsigned)f2b(v.x) | ((unsigned)f2b(v.y)<<16);
    p.y = (unsigned)f2b(v.z) | ((unsigned)f2b(v.w)<<16);
    *(uint2*)&xb[i*2] = p;
  }
}

// frag-ready: wf[((kcb*8+nt)*64+l)*8+j] = bf16(W[(kcb*32+8*(l>>4)+j)*128 + nt*16+(l&15)])
__global__ void k_repack(const float* __restrict__ W1, const float* __restrict__ W2,
                         const float* __restrict__ Ws, const float* __restrict__ Wn,
                         unsigned short* __restrict__ wf){
  int t = blockIdx.x*256+threadIdx.x;
  if(t >= 122880) return;
  const float* src; int rem;
  if(t < 8192){ src = W1; rem = t; }
  else {
    int u = t - 8192;
    int m = u >> 14; rem = u & 16383;
    if(m==0) src = W2;
    else if(m<=3) src = Ws + (size_t)(m-1)*HH*HH;
    else src = Wn + (size_t)(m-4)*HH*HH;
  }
  int j = rem&7, l=(rem>>3)&63, nt=(rem>>9)&7, kcb=rem>>12;
  int k = kcb*32 + 8*(l>>4) + j;
  int n = nt*16 + (l&15);
  wf[t] = f2b(src[(size_t)k*HH + n]);
}

// ---------------- mean aggregation: fp8 gather, 2-deep software pipeline ----------------
// lane = (q, c): quarter q owns edges beg+q, beg+q+4, ...; c indexes 8 feature bytes.
__global__ __launch_bounds__(256) void k_agg(const uint2* __restrict__ hf8, const int* __restrict__ csr,
                                             const int* __restrict__ rowoff, const float* __restrict__ invd,
                                             uint4* __restrict__ aggb){
  int wave=threadIdx.x>>6, lane=threadIdx.x&63;
  int n = blockIdx.x*4+wave;
  if(n>=NN) return;
  int beg=rowoff[n], end=rowoff[n+1];
  int c = lane&15, q=lane>>4;
  float a0=0.f,a1=0.f,a2=0.f,a3=0.f,a4=0.f,a5=0.f,a6=0.f,a7=0.f;

  int j0 = beg + q;
  int j1 = j0 + 4;
  bool h0 = j0 < end, h1 = j1 < end;
  uint2 u0, u1;
  if(h0) u0 = hf8[(size_t)csr[j0]*16 + c];
  if(h1) u1 = hf8[(size_t)csr[j1]*16 + c];
  while(h0){
    int j2 = j1 + 4;
    bool h2 = j2 < end;
    uint2 u2;
    if(h2) u2 = hf8[(size_t)csr[j2]*16 + c];
    {
      float d0[4], d1[4];
      f8dec4(u0.x,d0); f8dec4(u0.y,d1);
      a0+=d0[0]; a1+=d0[1]; a2+=d0[2]; a3+=d0[3];
      a4+=d1[0]; a5+=d1[1]; a6+=d1[2]; a7+=d1[3];
    }
    u0=u1; h0=h1; j1=j2; u1=u2; h1=h2;
  }

  a0+=__shfl_xor(a0,16); a1+=__shfl_xor(a1,16); a2+=__shfl_xor(a2,16); a3+=__shfl_xor(a3,16);
  a4+=__shfl_xor(a4,16); a5+=__shfl_xor(a5,16); a6+=__shfl_xor(a6,16); a7+=__shfl_xor(a7,16);
  a0+=__shfl_xor(a0,32); a1+=__shfl_xor(a1,32); a2+=__shfl_xor(a2,32); a3+=__shfl_xor(a3,32);
  a4+=__shfl_xor(a4,32); a5+=__shfl_xor(a5,32); a6+=__shfl_xor(a6,32); a7+=__shfl_xor(a7,32);
  if(q==0){
    float s=invd[n];
    uint4 p;
    p.x = (unsigned)f2b(a0*s) | ((unsigned)f2b(a1*s)<<16);
    p.y = (unsigned)f2b(a2*s) | ((unsigned)f2b(a3*s)<<16);
    p.z = (unsigned)f2b(a4*s) | ((unsigned)f2b(a5*s)<<16);
    p.w = (unsigned)f2b(a6*s) | ((unsigned)f2b(a7*s)<<16);
    aggb[(size_t)n*16 + c] = p;
  }
}

// ---------------- MFMA GEMM: 128 rows/block, B-fragments direct from L2 ----------------
// MEAN=1: skip out/hf8 writes, accumulate column sums into gsum instead.
template<int K, int DUAL, int RELU, int LN, int F8, int MEAN>
__global__ __launch_bounds__(256) void k_mfma(
    const unsigned short* __restrict__ A, const unsigned short* __restrict__ A2,
    const unsigned short* __restrict__ Wf, const unsigned short* __restrict__ Wf2,
    const float* __restrict__ bias, const float* __restrict__ lng, const float* __restrict__ lnb,
    unsigned short* __restrict__ out, unsigned char* __restrict__ hf8, float* __restrict__ gsum)
{
  constexpr int KC = K/32;
  __shared__ float sm[MEAN ? 4*128 : 4];
  int tid = threadIdx.x;
  int l = tid&63, wv = tid>>6;
  int grp = l>>4, lc = l&15;
  int node0 = blockIdx.x*128;
  const s8v* __restrict__ Wv  = (const s8v*)Wf;
  const s8v* __restrict__ Wv2 = (const s8v*)Wf2;
  f32x4 acc[2][8] = {};
  int r0 = node0 + wv*16 + lc;      if(r0>NN-1) r0=NN-1;
  int r1 = node0 + 64 + wv*16 + lc; if(r1>NN-1) r1=NN-1;
  #pragma unroll
  for(int kcb=0;kcb<KC;kcb++){
    s8v a0 = *(const s8v*)&A[(size_t)r0*K + kcb*32 + 8*grp];
    s8v a1 = *(const s8v*)&A[(size_t)r1*K + kcb*32 + 8*grp];
    s8v c0, c1;
    if(DUAL){
      c0 = *(const s8v*)&A2[(size_t)r0*K + kcb*32 + 8*grp];
      c1 = *(const s8v*)&A2[(size_t)r1*K + kcb*32 + 8*grp];
    }
    #pragma unroll
    for(int nt=0;nt<8;nt++){
      s8v b = Wv[(kcb*8+nt)*64 + l];
      acc[0][nt] = __builtin_amdgcn_mfma_f32_16x16x32_bf16(a0, b, acc[0][nt], 0,0,0);
      acc[1][nt] = __builtin_amdgcn_mfma_f32_16x16x32_bf16(a1, b, acc[1][nt], 0,0,0);
      if(DUAL){
        s8v b2 = Wv2[(kcb*8+nt)*64 + l];
        acc[0][nt] = __builtin_amdgcn_mfma_f32_16x16x32_bf16(c0, b2, acc[0][nt], 0,0,0);
        acc[1][nt] = __builtin_amdgcn_mfma_f32_16x16x32_bf16(c1, b2, acc[1][nt], 0,0,0);
      }
    }
  }
  float bc[8], gc[8], oc[8];
  #pragma unroll
  for(int nt=0;nt<8;nt++){
    bc[nt] = bias[nt*16+lc];
    if(LN){ gc[nt]=lng[nt*16+lc]; oc[nt]=lnb[nt*16+lc]; }
  }
  float msum[8];
  #pragma unroll
  for(int nt=0;nt<8;nt++) msum[nt]=0.f;
  #pragma unroll
  for(int s2=0;s2<2;s2++){
    #pragma unroll
    for(int r=0;r<4;r++){
      float x[8]; float s=0.f, ss=0.f;
      #pragma unroll
      for(int nt=0;nt<8;nt++){
        float v = acc[s2][nt][r] + bc[nt];
        if(RELU) v = fmaxf(v, 0.f);
        x[nt]=v; s+=v; ss+=v*v;
      }
      if(LN){
        #pragma unroll
        for(int m=1;m<=8;m<<=1){ s+=__shfl_xor(s,m); ss+=__shfl_xor(ss,m); }
        float mu = s*(1.0f/HH);
        float var = ss*(1.0f/HH) - mu*mu;
        float rs = rsqrtf(var + LNEPS);
        #pragma unroll
        for(int nt=0;nt<8;nt++) x[nt] = gc[nt]*(x[nt]-mu)*rs + oc[nt];
      }
      int node = node0 + s2*64 + wv*16 + grp*4 + r;
      if(node<NN){
        if(MEAN){
          #pragma unroll
          for(int nt=0;nt<8;nt++) msum[nt]+=x[nt];
        } else {
          #pragma unroll
          for(int nt=0;nt<8;nt++) out[(size_t)node*HH + nt*16 + lc] = f2b(x[nt]);
          if(F8){
            #pragma unroll
            for(int nt=0;nt<8;nt++) hf8[(size_t)node*HH + nt*16 + lc] = f8enc(x[nt]);
          }
        }
      }
    }
  }
  if(MEAN){
    #pragma unroll
    for(int nt=0;nt<8;nt++){
      msum[nt]+=__shfl_xor(msum[nt],16);
      msum[nt]+=__shfl_xor(msum[nt],32);
    }
    if(grp==0){
      #pragma unroll
      for(int nt=0;nt<8;nt++) sm[wv*128 + nt*16 + lc] = msum[nt];
    }
    __syncthreads();
    if(tid<128){
      float v = sm[tid] + sm[128+tid] + sm[256+tid] + sm[384+tid];
      atomicAdd(&gsum[tid], v);
    }
  }
}

// ---------------- output head ----------------
__global__ void k_out(const float* __restrict__ g, const float* __restrict__ Wout,
                      const float* __restrict__ bout, float* __restrict__ out){
  int o=threadIdx.x;
  if(o<OO){
    float acc=bout[o];
    for(int k=0;k<HH;k++) acc = fmaf(g[k]*(1.0f/NN), Wout[k*OO+o], acc);
    out[o]=acc;
  }
}

extern "C" void kernel_launch(void* const* d_in, const int* in_sizes, int n_in,
                              void* d_out, int out_size, void* d_ws, size_t ws_size,
                              hipStream_t stream){
  const float* nodes = (const float*)d_in[0];
  const int*   src   = (const int*)d_in[1];
  const int*   dst   = (const int*)d_in[2];
  const float* W_in1 = (const float*)d_in[3];
  const float* b_in1 = (const float*)d_in[4];
  const float* W_in2 = (const float*)d_in[5];
  const float* b_in2 = (const float*)d_in[6];
  const float* W_self  = (const float*)d_in[7];
  const float* W_neigh = (const float*)d_in[8];
  const float* b_sage  = (const float*)d_in[9];
  const float* ln_g    = (const float*)d_in[10];
  const float* ln_b    = (const float*)d_in[11];
  const float* W_out   = (const float*)d_in[12];
  const float* b_out   = (const float*)d_in[13];

  char* w=(char*)d_ws;
  unsigned short* hb   = (unsigned short*)w; w += (size_t)NN*HH*2;   // 25.6 MB
  unsigned short* aggb = (unsigned short*)w; w += (size_t)NN*HH*2;   // 25.6 MB
  unsigned short* xb   = (unsigned short*)w; w += (size_t)NN*FF*2;   // 12.8 MB
  unsigned char*  hf8  = (unsigned char*)w;  w += (size_t)NN*HH;     // 12.8 MB fp8 shadow
  unsigned short* wf   = (unsigned short*)w; w += (size_t)122880*2;
  unsigned* ebuf = (unsigned*)w; w += (size_t)NE*4;                  // 6.4 MB
  int* csr    = (int*)w;   w += (size_t)NE*4;                        // 6.4 MB
  int* rowoff = (int*)w;   w += (size_t)(NN+8)*4;
  float* invd = (float*)w; w += (size_t)NN*4;
  int* bcnt   = (int*)w;   w += (size_t)(NB+1)*4;
  int* boff   = (int*)w;   w += (size_t)(NB+1)*4;
  int* blockcnt=(int*)w;   w += (size_t)NB*256*4;
  int* pref   = (int*)w;   w += (size_t)NB*256*4;
  float* gsum = (float*)w; w += 128*4;

  hipMemsetAsync(bcnt, 0, (size_t)(NB+1)*4, stream);
  hipMemsetAsync(gsum, 0, 128*4, stream);

  k_bcount<<<NBLK,256,0,stream>>>(dst,bcnt,blockcnt);
  k_bscan<<<1,512,0,stream>>>(bcnt,boff,rowoff);
  k_prefix<<<NB,256,0,stream>>>(blockcnt,boff,pref);
  k_bscatter<<<NBLK,256,0,stream>>>(src,dst,pref,ebuf);
  k_bsort<<<NB,256,0,stream>>>(ebuf,bcnt,boff,rowoff,invd,csr);

  k_cvtin<<<((NN*FF/4)+255)/256,256,0,stream>>>(nodes,(unsigned*)xb, NN*FF/4);
  k_repack<<<(122880+255)/256,256,0,stream>>>(W_in1,W_in2,W_self,W_neigh,wf);

  const int GB2 = (NN+127)/128;
  // input MLP
  k_mfma<FF,0,1,0,0,0><<<GB2,256,0,stream>>>(xb,nullptr, wf, nullptr, b_in1,nullptr,nullptr, aggb, nullptr, nullptr);
  k_mfma<HH,0,0,0,1,0><<<GB2,256,0,stream>>>(aggb,nullptr, wf+8192, nullptr, b_in2,nullptr,nullptr, hb, hf8, nullptr);

  for(int l=0;l<NL;l++){
    k_agg<<<(NN+3)/4,256,0,stream>>>((const uint2*)hf8,csr,rowoff,invd,(uint4*)aggb);
    if(l<NL-1)
      k_mfma<HH,1,1,1,1,0><<<GB2,256,0,stream>>>(hb, aggb,
          wf+24576+(size_t)l*16384, wf+73728+(size_t)l*16384,
          b_sage+(size_t)l*HH, ln_g+(size_t)l*HH, ln_b+(size_t)l*HH, hb, hf8, nullptr);
    else
      k_mfma<HH,1,1,1,0,1><<<GB2,256,0,stream>>>(hb, aggb,
          wf+24576+(size_t)l*16384, wf+73728+(size_t)l*16384,
          b_sage+(size_t)l*HH, ln_g+(size_t)l*HH, ln_b+(size_t)l*HH, hb, nullptr, gsum);
  }
  k_out<<<1,64,0,stream>>>(gsum,W_out,b_out,(float*)d_out);
}